// Round 12
// baseline (3969.908 us; speedup 1.0000x reference)
//
#include <hip/hip_runtime.h>

typedef __attribute__((ext_vector_type(8))) short short8;
typedef __attribute__((ext_vector_type(4))) float floatx4;

#define BB    512
#define HH    200
#define NSTEP 511
#define NG    32          // groups
#define NM    8           // members (blocks) per group
#define GW2   208         // gates LDS row stride (f32): 208%32=16 -> 2-way (free)

// ---- ws layout (u32 words) ----
#define OW2   0                          // [8][112*224]  W2 slice, bf16 pairs, K=448
#define OW1   (OW2 + 8*112*224)          // [8][112*128]  W1 slice, K=256
#define OF1   (OW1 + 8*112*128)          // [208][128]    F1 FULL, K=256 ([h2|x|pad]); rows 200..207 zero
#define OF2   (OF1 + 208*128)            // [48*112]      F2 full, K=224
#define OFC0  (OF2 + 48*112)             // [24*48] f32   fc0^T
#define OB1   (OFC0 + 1152)              // [8][112] f32  b1 sliced
#define OB2   (OB1 + 896)                // [8][112] f32  b2 sliced
#define OFLG  (OB2 + 896)                // [32*2*8] flags (zeroed every call)
#define OEXC  (OFLG + 512)               // [32][2][8][400] f32 exchange payload
#define WS_TOT (OEXC + NG*2*NM*400)

// payload: workgroup-scope store (write-back; L1 write-through -> lands in shared L2)
#define PST(p, v) __hip_atomic_store((p), (v), __ATOMIC_RELAXED, __HIP_MEMORY_SCOPE_WORKGROUP)
// flags: agent scope
#define AST(p, v) __hip_atomic_store((p), (v), __ATOMIC_RELAXED, __HIP_MEMORY_SCOPE_AGENT)
// cross-block loads: agent scope (bypass stale L1)
#define ALD(p)    __hip_atomic_load((p), __ATOMIC_RELAXED, __HIP_MEMORY_SCOPE_AGENT)

__device__ __forceinline__ unsigned short f2bf(float f) {
    unsigned u = __float_as_uint(f);
    unsigned r = (u + 0x7fffu + ((u >> 16) & 1u)) >> 16;
    return (unsigned short)r;
}
__device__ __forceinline__ float sigm(float x) { return 1.0f / (1.0f + __expf(-x)); }
__device__ __forceinline__ float tanh_fast(float x) {
    float e = __expf(-2.0f * fabsf(x));
    float t = 1.0f - 2.0f * e / (1.0f + e);
    return copysignf(t, x);
}

// -------------------- prep: pack weights; zero flags --------------------
__global__ void prep_kernel(const float* __restrict__ l1_wih, const float* __restrict__ l1_whh,
                            const float* __restrict__ l1_bih, const float* __restrict__ l1_bhh,
                            const float* __restrict__ l2_wih, const float* __restrict__ l2_whh,
                            const float* __restrict__ l2_bih, const float* __restrict__ l2_bhh,
                            const float* __restrict__ fc1_w, const float* __restrict__ fc2_w,
                            const float* __restrict__ fc0_w, unsigned* __restrict__ ws)
{
    int idx = blockIdx.x * blockDim.x + threadIdx.x;
    int stride = gridDim.x * blockDim.x;
    for (int i = idx; i < OEXC; i += stride) {
        if (i < OW1) {                                   // W2 slices [m][112][224 pairs]
            int r0 = i - OW2, m = r0 / (112*224), rem = r0 % (112*224);
            int r = rem / 224, kp = rem % 224;
            int grow = (r < 100) ? 200*(r/25) + 25*m + (r%25) : -1;
            float a = 0.f, b = 0.f;
            if (grow >= 0) {
                int k0 = 2*kp, k1 = k0 + 1;
                a = (k0 < 248) ? l2_wih[grow*248 + k0] : l2_whh[grow*HH + k0 - 248];
                b = (k1 < 248) ? l2_wih[grow*248 + k1] : l2_whh[grow*HH + k1 - 248];
            }
            ws[i] = (unsigned)f2bf(a) | ((unsigned)f2bf(b) << 16);
        } else if (i < OF1) {                            // W1 slices [m][112][128 pairs]
            int r0 = i - OW1, m = r0 / (112*128), rem = r0 % (112*128);
            int r = rem / 128, kp = rem % 128;
            int grow = (r < 100) ? 200*(r/25) + 25*m + (r%25) : -1;
            float a = 0.f, b = 0.f;
            if (grow >= 0) {
                int k0 = 2*kp, k1 = k0 + 1;
                a = (k0 < 48) ? l1_wih[grow*48 + k0] : (k0 < 248 ? l1_whh[grow*HH + k0 - 48] : 0.f);
                b = (k1 < 48) ? l1_wih[grow*48 + k1] : (k1 < 248 ? l1_whh[grow*HH + k1 - 48] : 0.f);
            }
            ws[i] = (unsigned)f2bf(a) | ((unsigned)f2bf(b) << 16);
        } else if (i < OF2) {                            // F1 FULL [208][128 pairs]
            int r0 = i - OF1, n = r0 / 128, kp = r0 % 128;
            int k0 = 2*kp, k1 = k0 + 1;
            float a = (n < 200 && k0 < 248) ? fc1_w[n*248 + k0] : 0.f;
            float b = (n < 200 && k1 < 248) ? fc1_w[n*248 + k1] : 0.f;
            ws[i] = (unsigned)f2bf(a) | ((unsigned)f2bf(b) << 16);
        } else if (i < OFC0) {                           // F2 full [48][112 pairs]
            int r0 = i - OF2, n = r0 / 112, kp = r0 % 112;
            int k0 = 2*kp, k1 = k0 + 1;
            float a = (k0 < 200) ? fc2_w[n*HH + k0] : 0.f;
            float b = (k1 < 200) ? fc2_w[n*HH + k1] : 0.f;
            ws[i] = (unsigned)f2bf(a) | ((unsigned)f2bf(b) << 16);
        } else if (i < OB1) {                            // fc0^T f32
            int r = i - OFC0, k = r / 48, j = r % 48;
            ws[i] = __float_as_uint(fc0_w[j*24 + k]);
        } else if (i < OB2) {                            // b1 sliced
            int r0 = i - OB1, m = r0 / 112, r = r0 % 112;
            int grow = (r < 100) ? 200*(r/25) + 25*m + (r%25) : -1;
            ws[i] = __float_as_uint(grow >= 0 ? l1_bih[grow] + l1_bhh[grow] : 0.f);
        } else if (i < OFLG) {                           // b2 sliced
            int r0 = i - OB2, m = r0 / 112, r = r0 % 112;
            int grow = (r < 100) ? 200*(r/25) + 25*m + (r%25) : -1;
            ws[i] = __float_as_uint(grow >= 0 ? l2_bih[grow] + l2_bhh[grow] : 0.f);
        } else {
            ws[i] = 0u;                                  // flags := 0 every call
        }
    }
}

// write one bf16 element (row m, k-index k) into a pre-fragmented A-buffer
__device__ __forceinline__ void put16(short8* buf, int k, int m, unsigned short v) {
    int kt = k >> 5, kk = k & 31;
    ((unsigned short*)buf)[(((kt << 6) + m + ((kk >> 3) << 4)) << 3) + (kk & 7)] = v;
}

// -------------------- main: 256 blocks (32 groups x 8 members), 2 exchanges/step --------------------
__global__ __launch_bounds__(1024, 4)
void lstm_sync(const float* __restrict__ tactiles, const float* __restrict__ actions,
               const float* __restrict__ fc0_b, const float* __restrict__ fc1_b,
               const float* __restrict__ fc2_b, const int* __restrict__ ctxp,
               unsigned* __restrict__ wsu, float* __restrict__ out)
{
    const int tid  = threadIdx.x;
    const int lane = tid & 63, wave = tid >> 6;
    const int ln   = lane & 15, hi = lane >> 4;
    const int g    = blockIdx.x % NG;
    const int m    = blockIdx.x / NG;
    const int r0   = g * 16;
    const int ctx  = ctxp[0];

    const short8* ws8 = (const short8*)wsu;
    unsigned* flg = wsu + OFLG;
    float*    exc = (float*)(wsu + OEXC);

    __shared__ short8 sW1[112 * 33];   // W1 slice: row*33 + kf*4 + hi
    __shared__ short8 sF2[48 * 29];    // F2 full
    __shared__ short8 XA1[8 * 64];     // [x(48) | h1(200)] pad 256
    __shared__ short8 XA2[14 * 64];    // [h1 | out0(48) | h2] = 448
    __shared__ short8 XA3[8 * 64];     // [h2 | x(48)] pad 256
    __shared__ short8 XA4[7 * 64];     // [o3(200)] pad 224
    __shared__ float gates[16 * GW2];
    __shared__ float b1s[112], b2s[112], f1bs[200], f2bs[48], f0bs[48];
    __shared__ float fc0s[24 * 48];
    __shared__ float st6[16][6], ac6[16][6];

    // ---- init: weights -> LDS/regs (once) ----
    {
        const short8* w1b = ws8 + OW1/4 + m * 3584;          // 112*128/4
        for (int i = tid; i < 3584; i += 1024) sW1[(i >> 5) * 33 + (i & 31)] = w1b[i];
        const short8* f2b = ws8 + OF2/4;                     // 48*112/4 = 1344
        for (int i = tid; i < 1344; i += 1024) sF2[(i / 28) * 29 + (i % 28)] = f2b[i];
        short8 z = {0,0,0,0,0,0,0,0};
        for (int i = tid; i < 2368; i += 1024) {
            if (i < 512) XA1[i] = z;
            else if (i < 1408) XA2[i - 512] = z;
            else if (i < 1920) XA3[i - 1408] = z;
            else XA4[i - 1920] = z;
        }
    }
    short8 w2r[14], f1r[8];
    {
        short8 z = {0,0,0,0,0,0,0,0};
        #pragma unroll
        for (int kf = 0; kf < 14; ++kf) w2r[kf] = z;
        #pragma unroll
        for (int kf = 0; kf < 8; ++kf) f1r[kf] = z;
        if (wave < 7) {
            const short8* w2b = ws8 + (size_t)m * 6272;      // 112*224/4
            const int rr = wave * 16 + ln;
            #pragma unroll
            for (int kf = 0; kf < 14; ++kf) w2r[kf] = w2b[rr * 56 + kf * 4 + hi];
        }
        if (wave < 13) {                                     // full F1: tile `wave`
            const short8* f1b = ws8 + OF1/4;                 // 208 rows x 32 short8
            const int rr = wave * 16 + ln;
            #pragma unroll
            for (int kf = 0; kf < 8; ++kf) f1r[kf] = f1b[rr * 32 + kf * 4 + hi];
        }
    }
    for (int i = tid; i < 112; i += 1024) {
        b1s[i] = __uint_as_float(wsu[OB1 + m*112 + i]);
        b2s[i] = __uint_as_float(wsu[OB2 + m*112 + i]);
    }
    if (tid < 200) f1bs[tid] = fc1_b[tid];
    if (tid < 48)  { f2bs[tid] = fc2_b[tid]; f0bs[tid] = fc0_b[tid]; }
    for (int i = tid; i < 1152; i += 1024) fc0s[i] = __uint_as_float(wsu[OFC0 + i]);
    if (tid < 96) { int r = tid / 6, k = tid % 6; st6[r][k] = actions[(size_t)(r0 + r) * 6 + k]; }
    float c1r = 0.f, c2r = 0.f;
    __syncthreads();

    for (int t = 0; t < NSTEP; ++t) {
        // ---- P0: context x from tactiles ----
        if (t < ctx) {
            if (tid < 768) {
                int r = tid / 48, j = tid % 48;
                unsigned short xb = f2bf(tactiles[((size_t)t * BB + r0 + r) * 48 + j]);
                put16(XA1, j, r, xb);
                put16(XA3, 200 + j, r, xb);
            }
            __syncthreads();
        }

        // ---- A: gates1 = XA1 @ W1_slice (waves 0..6) + ac6 prefetch ----
        if (wave < 7) {
            floatx4 acc = {0.f, 0.f, 0.f, 0.f};
            const int rbase = (wave * 16 + ln) * 33 + hi;
            #pragma unroll
            for (int kf = 0; kf < 8; ++kf)
                acc = __builtin_amdgcn_mfma_f32_16x16x32_bf16(XA1[(kf << 6) + lane], sW1[rbase + kf*4], acc, 0, 0, 0);
            int col = wave * 16 + ln, m0 = hi * 4;
            gates[(m0+0)*GW2 + col] = acc[0];
            gates[(m0+1)*GW2 + col] = acc[1];
            gates[(m0+2)*GW2 + col] = acc[2];
            gates[(m0+3)*GW2 + col] = acc[3];
        }
        if (tid >= 928) {
            int q = tid - 928, r = q / 6, k = q % 6;
            ac6[r][k] = actions[((size_t)(t + 1) * BB + r0 + r) * 6 + k];
        }
        __syncthreads();

        // ---- pw1: h1/c1 (tid<400) + out0 (tid<768); publish h1 ----
        if (tid < 400) {
            int r = tid / 25, f = tid % 25;
            float gi = gates[r*GW2 + f]      + b1s[f];
            float gf = gates[r*GW2 + 25 + f] + b1s[25 + f];
            float gg = gates[r*GW2 + 50 + f] + b1s[50 + f];
            float go = gates[r*GW2 + 75 + f] + b1s[75 + f];
            float c = sigm(gf) * c1r + sigm(gi) * tanh_fast(gg);
            c1r = c;
            float h = sigm(go) * tanh_fast(c);
            unsigned short hb = f2bf(h);
            int kg = 25*m + f;
            put16(XA1, 48 + kg, r, hb);
            put16(XA2, kg, r, hb);
            PST(&exc[((g*2 + 0)*NM + m)*400 + tid], h);
        }
        if (tid < 768) {
            int r = tid / 48, j = tid % 48;
            float acc = f0bs[j];
            #pragma unroll
            for (int k = 0; k < 24; ++k) {
                float tv = (k < 12) ? st6[r][k % 6] : ac6[r][k % 6];
                acc += tv * fc0s[k * 48 + j];
            }
            put16(XA2, 200 + j, r, f2bf(fmaxf(acc, 0.f)));
        }
        __syncthreads();    // drains vmcnt -> h1 payload in (shared) L2

        // ---- exchange h1 ----
        if (tid == 0) AST(&flg[(g*2 + 0)*NM + m], (unsigned)(t + 1));
        if (tid < 8 && tid != m) {
            while (ALD(&flg[(g*2 + 0)*NM + tid]) != (unsigned)(t + 1))
                __builtin_amdgcn_s_sleep(1);
        }
        __syncthreads();
        for (int q = tid; q < 3200; q += 1024) {
            int mm = q / 400;
            if (mm == m) continue;
            int qq = q % 400, r = qq / 25, f = qq % 25;
            float v = ALD(&exc[((g*2 + 0)*NM + mm)*400 + qq]);
            unsigned short hb = f2bf(v);
            int kg = 25*mm + f;
            put16(XA1, 48 + kg, r, hb);
            put16(XA2, kg, r, hb);
        }
        __syncthreads();

        // ---- B: gates2 = XA2 @ W2_slice (register-resident weights) ----
        if (wave < 7) {
            floatx4 acc = {0.f, 0.f, 0.f, 0.f};
            #pragma unroll
            for (int kf = 0; kf < 14; ++kf)
                acc = __builtin_amdgcn_mfma_f32_16x16x32_bf16(XA2[(kf << 6) + lane], w2r[kf], acc, 0, 0, 0);
            int col = wave * 16 + ln, m0 = hi * 4;
            gates[(m0+0)*GW2 + col] = acc[0];
            gates[(m0+1)*GW2 + col] = acc[1];
            gates[(m0+2)*GW2 + col] = acc[2];
            gates[(m0+3)*GW2 + col] = acc[3];
        }
        __syncthreads();

        // ---- pw2: h2/c2; publish h2 ----
        if (tid < 400) {
            int r = tid / 25, f = tid % 25;
            float gi = gates[r*GW2 + f]      + b2s[f];
            float gf = gates[r*GW2 + 25 + f] + b2s[25 + f];
            float gg = gates[r*GW2 + 50 + f] + b2s[50 + f];
            float go = gates[r*GW2 + 75 + f] + b2s[75 + f];
            float c = sigm(gf) * c2r + sigm(gi) * tanh_fast(gg);
            c2r = c;
            float h = sigm(go) * tanh_fast(c);
            unsigned short hb = f2bf(h);
            int kg = 25*m + f;
            put16(XA2, 248 + kg, r, hb);
            put16(XA3, kg, r, hb);
            PST(&exc[((g*2 + 1)*NM + m)*400 + tid], h);
        }
        __syncthreads();    // drains vmcnt -> h2 payload in L2

        // ---- exchange h2 ----
        if (tid == 0) AST(&flg[(g*2 + 1)*NM + m], (unsigned)(t + 1));
        if (tid < 8 && tid != m) {
            while (ALD(&flg[(g*2 + 1)*NM + tid]) != (unsigned)(t + 1))
                __builtin_amdgcn_s_sleep(1);
        }
        __syncthreads();
        for (int q = tid; q < 3200; q += 1024) {
            int mm = q / 400;
            if (mm == m) continue;
            int qq = q % 400, r = qq / 25, f = qq % 25;
            float v = ALD(&exc[((g*2 + 1)*NM + mm)*400 + qq]);
            unsigned short hb = f2bf(v);
            int kg = 25*mm + f;
            put16(XA2, 248 + kg, r, hb);
            put16(XA3, kg, r, hb);
        }
        __syncthreads();

        // ---- C: fc1 FULL = XA3 @ F1 (13 tiles, one per wave 0..12, register weights) ----
        if (wave < 13) {
            floatx4 acc = {0.f, 0.f, 0.f, 0.f};
            #pragma unroll
            for (int kf = 0; kf < 8; ++kf)
                acc = __builtin_amdgcn_mfma_f32_16x16x32_bf16(XA3[(kf << 6) + lane], f1r[kf], acc, 0, 0, 0);
            int col = wave * 16 + ln, m0 = hi * 4;
            gates[(m0+0)*GW2 + col] = acc[0];
            gates[(m0+1)*GW2 + col] = acc[1];
            gates[(m0+2)*GW2 + col] = acc[2];
            gates[(m0+3)*GW2 + col] = acc[3];
        }
        __syncthreads();

        // ---- pw3: o3 = tanh (full 16x200, local) ----
        #pragma unroll
        for (int i = 0; i < 4; ++i) {
            int it = tid + 1024 * i;
            if (it < 3200) {
                int r = it / 200, f = it % 200;
                float v = tanh_fast(gates[r*GW2 + f] + f1bs[f]);
                put16(XA4, f, r, f2bf(v));
            }
        }
        __syncthreads();

        // ---- D: fc2 full (waves 0..2) ----
        if (wave < 3) {
            floatx4 acc = {0.f, 0.f, 0.f, 0.f};
            const int rbase = (wave * 16 + ln) * 29 + hi;
            #pragma unroll
            for (int kf = 0; kf < 7; ++kf)
                acc = __builtin_amdgcn_mfma_f32_16x16x32_bf16(XA4[(kf << 6) + lane], sF2[rbase + kf*4], acc, 0, 0, 0);
            int col = wave * 16 + ln, m0 = hi * 4;
            gates[(m0+0)*GW2 + col] = acc[0];
            gates[(m0+1)*GW2 + col] = acc[1];
            gates[(m0+2)*GW2 + col] = acc[2];
            gates[(m0+3)*GW2 + col] = acc[3];
        }
        __syncthreads();

        // ---- pw4: out4 = tanh; store (member 0); feed back as next x ----
        if (tid < 768) {
            int r = tid / 48, j = tid % 48;
            float v = tanh_fast(gates[r*GW2 + j] + f2bs[j]);
            unsigned short xb = f2bf(v);
            put16(XA1, j, r, xb);
            put16(XA3, 200 + j, r, xb);
            if (m == 0 && t >= ctx - 1)
                out[((size_t)(t - (ctx - 1)) * BB + r0 + r) * 48 + j] = v;
        }
        __syncthreads();
    }
}

extern "C" void kernel_launch(void* const* d_in, const int* in_sizes, int n_in,
                              void* d_out, int out_size, void* d_ws, size_t ws_size,
                              hipStream_t stream)
{
    const float* tactiles = (const float*)d_in[0];
    const float* actions  = (const float*)d_in[1];
    const float* fc0_w    = (const float*)d_in[2];
    const float* fc0_b    = (const float*)d_in[3];
    const float* l1_wih   = (const float*)d_in[4];
    const float* l1_whh   = (const float*)d_in[5];
    const float* l1_bih   = (const float*)d_in[6];
    const float* l1_bhh   = (const float*)d_in[7];
    const float* l2_wih   = (const float*)d_in[8];
    const float* l2_whh   = (const float*)d_in[9];
    const float* l2_bih   = (const float*)d_in[10];
    const float* l2_bhh   = (const float*)d_in[11];
    const float* fc1_w    = (const float*)d_in[12];
    const float* fc1_b    = (const float*)d_in[13];
    const float* fc2_w    = (const float*)d_in[14];
    const float* fc2_b    = (const float*)d_in[15];
    const int*   ctxp     = (const int*)d_in[16];
    unsigned* ws = (unsigned*)d_ws;
    float* out = (float*)d_out;

    hipLaunchKernelGGL(prep_kernel, dim3(512), dim3(256), 0, stream,
                       l1_wih, l1_whh, l1_bih, l1_bhh,
                       l2_wih, l2_whh, l2_bih, l2_bhh,
                       fc1_w, fc2_w, fc0_w, ws);
    hipLaunchKernelGGL(lstm_sync, dim3(256), dim3(1024), 0, stream,
                       tactiles, actions, fc0_b, fc1_b, fc2_b, ctxp, ws, out);
}

// Round 14
// 3645.461 us; speedup vs baseline: 1.0890x; 1.0890x over previous
//
#include <hip/hip_runtime.h>

typedef __attribute__((ext_vector_type(8))) short short8;
typedef __attribute__((ext_vector_type(4))) float floatx4;

#define BB    512
#define HH    200
#define NSTEP 511
#define NG    32          // groups
#define NM    8           // members (blocks) per group
#define GWL   116         // gates LDS row stride (f32)

// ---- ws layout (u32 words) ----
#define OW2   0                          // [8][112*224]  W2 slice, bf16 pairs, K=448 row-major
#define OW1   (OW2 + 8*112*224)          // [8][112*128]  W1 slice, K=256
#define OF1   (OW1 + 8*112*128)          // [8][32*128]   fc1 slice, K=256
#define OF2   (OF1 + 8*32*128)           // [48*112]      fc2 full, K=224
#define OFC0  (OF2 + 48*112)             // [24*48] f32   fc0^T
#define OB1   (OFC0 + 1152)              // [8][112] f32  b1 sliced
#define OB2   (OB1 + 896)                // [8][112] f32
#define OFB1  (OB2 + 896)                // [8][32]  f32  fc1_b sliced (filled by prep_fc1b)
#define OFLG  (OFB1 + 256)               // [32*3*8] flags (zeroed every call)
#define OEXC  (OFLG + 768)               // [32][3][8][400] f32 exchange payload
#define WS_TOT (OEXC + NG*3*NM*400)

// payload: workgroup-scope store (write-back; L1 write-through -> lands in shared L2)
#define PST(p, v) __hip_atomic_store((p), (v), __ATOMIC_RELAXED, __HIP_MEMORY_SCOPE_WORKGROUP)
// flags: agent scope
#define AST(p, v) __hip_atomic_store((p), (v), __ATOMIC_RELAXED, __HIP_MEMORY_SCOPE_AGENT)
// cross-block loads: agent scope (bypass stale L1)
#define ALD(p)    __hip_atomic_load((p), __ATOMIC_RELAXED, __HIP_MEMORY_SCOPE_AGENT)

__device__ __forceinline__ unsigned short f2bf(float f) {
    unsigned u = __float_as_uint(f);
    unsigned r = (u + 0x7fffu + ((u >> 16) & 1u)) >> 16;
    return (unsigned short)r;
}
__device__ __forceinline__ float sigm(float x) { return 1.0f / (1.0f + __expf(-x)); }
__device__ __forceinline__ float tanh_fast(float x) {
    float e = __expf(-2.0f * fabsf(x));
    float t = 1.0f - 2.0f * e / (1.0f + e);
    return copysignf(t, x);
}

// -------------------- prep: pack weights into per-member slices; zero flags --------------------
__global__ void prep_kernel(const float* __restrict__ l1_wih, const float* __restrict__ l1_whh,
                            const float* __restrict__ l1_bih, const float* __restrict__ l1_bhh,
                            const float* __restrict__ l2_wih, const float* __restrict__ l2_whh,
                            const float* __restrict__ l2_bih, const float* __restrict__ l2_bhh,
                            const float* __restrict__ fc1_w, const float* __restrict__ fc2_w,
                            const float* __restrict__ fc0_w, unsigned* __restrict__ ws)
{
    int idx = blockIdx.x * blockDim.x + threadIdx.x;
    int stride = gridDim.x * blockDim.x;
    for (int i = idx; i < OEXC; i += stride) {
        if (i < OW1) {                                   // W2 slices [m][112][224 pairs]
            int r0 = i - OW2, m = r0 / (112*224), rem = r0 % (112*224);
            int r = rem / 224, kp = rem % 224;
            int grow = (r < 100) ? 200*(r/25) + 25*m + (r%25) : -1;
            float a = 0.f, b = 0.f;
            if (grow >= 0) {
                int k0 = 2*kp, k1 = k0 + 1;
                a = (k0 < 248) ? l2_wih[grow*248 + k0] : l2_whh[grow*HH + k0 - 248];
                b = (k1 < 248) ? l2_wih[grow*248 + k1] : l2_whh[grow*HH + k1 - 248];
            }
            ws[i] = (unsigned)f2bf(a) | ((unsigned)f2bf(b) << 16);
        } else if (i < OF1) {                            // W1 slices [m][112][128 pairs]
            int r0 = i - OW1, m = r0 / (112*128), rem = r0 % (112*128);
            int r = rem / 128, kp = rem % 128;
            int grow = (r < 100) ? 200*(r/25) + 25*m + (r%25) : -1;
            float a = 0.f, b = 0.f;
            if (grow >= 0) {
                int k0 = 2*kp, k1 = k0 + 1;
                a = (k0 < 48) ? l1_wih[grow*48 + k0] : (k0 < 248 ? l1_whh[grow*HH + k0 - 48] : 0.f);
                b = (k1 < 48) ? l1_wih[grow*48 + k1] : (k1 < 248 ? l1_whh[grow*HH + k1 - 48] : 0.f);
            }
            ws[i] = (unsigned)f2bf(a) | ((unsigned)f2bf(b) << 16);
        } else if (i < OF2) {                            // fc1 slices [m][32][128 pairs]
            int r0 = i - OF1, m = r0 / (32*128), rem = r0 % (32*128);
            int r = rem / 128, kp = rem % 128;
            int frow = (r < 25) ? 25*m + r : -1;
            float a = 0.f, b = 0.f;
            if (frow >= 0) {
                int k0 = 2*kp, k1 = k0 + 1;
                a = (k0 < 248) ? fc1_w[frow*248 + k0] : 0.f;
                b = (k1 < 248) ? fc1_w[frow*248 + k1] : 0.f;
            }
            ws[i] = (unsigned)f2bf(a) | ((unsigned)f2bf(b) << 16);
        } else if (i < OFC0) {                           // fc2 full [48][112 pairs]
            int r0 = i - OF2, n = r0 / 112, kp = r0 % 112;
            int k0 = 2*kp, k1 = k0 + 1;
            float a = (k0 < 200) ? fc2_w[n*HH + k0] : 0.f;
            float b = (k1 < 200) ? fc2_w[n*HH + k1] : 0.f;
            ws[i] = (unsigned)f2bf(a) | ((unsigned)f2bf(b) << 16);
        } else if (i < OB1) {                            // fc0^T f32
            int r = i - OFC0, k = r / 48, j = r % 48;
            ws[i] = __float_as_uint(fc0_w[j*24 + k]);
        } else if (i < OB2) {                            // b1 sliced
            int r0 = i - OB1, m = r0 / 112, r = r0 % 112;
            int grow = (r < 100) ? 200*(r/25) + 25*m + (r%25) : -1;
            ws[i] = __float_as_uint(grow >= 0 ? l1_bih[grow] + l1_bhh[grow] : 0.f);
        } else if (i < OFB1) {                           // b2 sliced
            int r0 = i - OB2, m = r0 / 112, r = r0 % 112;
            int grow = (r < 100) ? 200*(r/25) + 25*m + (r%25) : -1;
            ws[i] = __float_as_uint(grow >= 0 ? l2_bih[grow] + l2_bhh[grow] : 0.f);
        } else {
            ws[i] = 0u;   // fc1_b slice placeholder (filled by prep_fc1b after) + flags := 0
        }
    }
}

// fc1_b slice fill — launched after prep_kernel on the same stream (ordered)
__global__ void prep_fc1b(const float* __restrict__ fc1_b, unsigned* __restrict__ ws)
{
    int i = blockIdx.x * blockDim.x + threadIdx.x;
    if (i < 256) {
        int m = i / 32, r = i % 32;
        ws[OFB1 + i] = __float_as_uint(r < 25 ? fc1_b[25*m + r] : 0.f);
    }
}

// write one bf16 element (row m, k-index k) into a pre-fragmented A-buffer
__device__ __forceinline__ void put16(short8* buf, int k, int m, unsigned short v) {
    int kt = k >> 5, kk = k & 31;
    ((unsigned short*)buf)[(((kt << 6) + m + ((kk >> 3) << 4)) << 3) + (kk & 7)] = v;
}

// -------------------- main: 256 blocks (32 groups x 8 members), weight-stationary --------------------
// Exchange protocol (validated rounds 10-12): payload PST (workgroup) -> drain barrier ->
// flag AST (agent) -> 8-thread poll -> barrier -> consume -> barrier. The poll->barrier
// separation before consume is REQUIRED in practice (round-13's immediate-consume raced).
__global__ __launch_bounds__(1024, 4)
void lstm_sync(const float* __restrict__ tactiles, const float* __restrict__ actions,
               const float* __restrict__ fc0_b, const float* __restrict__ fc2_b,
               const int* __restrict__ ctxp, unsigned* __restrict__ wsu,
               float* __restrict__ out)
{
    const int tid  = threadIdx.x;
    const int lane = tid & 63, wave = tid >> 6;
    const int ln   = lane & 15, hi = lane >> 4;
    const int g    = blockIdx.x % NG;        // group (same XCD for all members)
    const int m    = blockIdx.x / NG;        // member 0..7 (feature slice)
    const int r0   = g * 16;                 // batch rows of this group
    const int ctx  = ctxp[0];

    const short8* ws8 = (const short8*)wsu;
    unsigned* flg = wsu + OFLG;
    float*    exc = (float*)(wsu + OEXC);

    __shared__ short8 sW1[112 * 33];   // row*33 + kf*4 + hi
    __shared__ short8 sF1[32 * 33];
    __shared__ short8 sF2[48 * 29];
    __shared__ short8 XA1[8 * 64];     // [x(48) | h1(200)] pad 256
    __shared__ short8 XA2[14 * 64];    // [h1 | out0(48) | h2] = 448
    __shared__ short8 XA3[8 * 64];     // [h2 | x(48)] pad 256
    __shared__ short8 XA4[7 * 64];     // [o3(200)] pad 224
    __shared__ float gates[16 * GWL];
    __shared__ float b1s[112], b2s[112], f1bs[32], f2bs[48], f0bs[48];
    __shared__ float fc0s[24 * 48];
    __shared__ float st6[16][6], ac6[16][6];

    // ---- init: weights -> LDS/regs (once) ----
    {
        const short8* w1b = ws8 + OW1/4 + m * 3584;          // 112*128/4
        for (int i = tid; i < 3584; i += 1024) sW1[(i >> 5) * 33 + (i & 31)] = w1b[i];
        const short8* f1b = ws8 + OF1/4 + m * 1024;          // 32*128/4
        for (int i = tid; i < 1024; i += 1024) sF1[(i >> 5) * 33 + (i & 31)] = f1b[i];
        const short8* f2b = ws8 + OF2/4;                     // 48*112/4 = 1344
        for (int i = tid; i < 1344; i += 1024) sF2[(i / 28) * 29 + (i % 28)] = f2b[i];
        short8 z = {0,0,0,0,0,0,0,0};
        for (int i = tid; i < 2368; i += 1024) {
            if (i < 512) XA1[i] = z;
            else if (i < 1408) XA2[i - 512] = z;
            else if (i < 1920) XA3[i - 1408] = z;
            else XA4[i - 1920] = z;
        }
    }
    short8 w2r[14];
    {
        short8 z = {0,0,0,0,0,0,0,0};
        #pragma unroll
        for (int kf = 0; kf < 14; ++kf) w2r[kf] = z;
        if (wave < 7) {
            const short8* w2b = ws8 + (size_t)m * 6272;      // 112*224/4
            const int rr = wave * 16 + ln;
            #pragma unroll
            for (int kf = 0; kf < 14; ++kf) w2r[kf] = w2b[rr * 56 + kf * 4 + hi];
        }
    }
    for (int i = tid; i < 112; i += 1024) {
        b1s[i] = __uint_as_float(wsu[OB1 + m*112 + i]);
        b2s[i] = __uint_as_float(wsu[OB2 + m*112 + i]);
    }
    if (tid < 32)  f1bs[tid] = __uint_as_float(wsu[OFB1 + m*32 + tid]);
    if (tid < 48)  { f2bs[tid] = fc2_b[tid]; f0bs[tid] = fc0_b[tid]; }
    for (int i = tid; i < 1152; i += 1024) fc0s[i] = __uint_as_float(wsu[OFC0 + i]);
    if (tid < 96) { int r = tid / 6, k = tid % 6; st6[r][k] = actions[(size_t)(r0 + r) * 6 + k]; }
    float c1r = 0.f, c2r = 0.f;
    __syncthreads();

    for (int t = 0; t < NSTEP; ++t) {
        // ---- P0: context x from tactiles ----
        if (t < ctx) {
            if (tid < 768) {
                int r = tid / 48, j = tid % 48;
                unsigned short xb = f2bf(tactiles[((size_t)t * BB + r0 + r) * 48 + j]);
                put16(XA1, j, r, xb);
                put16(XA3, 200 + j, r, xb);
            }
            __syncthreads();
        }

        // ---- A: gates1 = XA1 @ W1_slice (waves 0..6) + ac6 prefetch ----
        if (wave < 7) {
            floatx4 acc = {0.f, 0.f, 0.f, 0.f};
            const int rbase = (wave * 16 + ln) * 33 + hi;
            #pragma unroll
            for (int kf = 0; kf < 8; ++kf)
                acc = __builtin_amdgcn_mfma_f32_16x16x32_bf16(XA1[(kf << 6) + lane], sW1[rbase + kf*4], acc, 0, 0, 0);
            int col = wave * 16 + ln, m0 = hi * 4;
            gates[(m0+0)*GWL + col] = acc[0];
            gates[(m0+1)*GWL + col] = acc[1];
            gates[(m0+2)*GWL + col] = acc[2];
            gates[(m0+3)*GWL + col] = acc[3];
        }
        if (tid >= 928) {
            int q = tid - 928, r = q / 6, k = q % 6;
            ac6[r][k] = actions[((size_t)(t + 1) * BB + r0 + r) * 6 + k];
        }
        __syncthreads();

        // ---- pw1: h1/c1 (tid<400) + out0 (tid<768); publish h1 ----
        if (tid < 400) {
            int r = tid / 25, f = tid % 25;
            float gi = gates[r*GWL + f]      + b1s[f];
            float gf = gates[r*GWL + 25 + f] + b1s[25 + f];
            float gg = gates[r*GWL + 50 + f] + b1s[50 + f];
            float go = gates[r*GWL + 75 + f] + b1s[75 + f];
            float c = sigm(gf) * c1r + sigm(gi) * tanh_fast(gg);
            c1r = c;
            float h = sigm(go) * tanh_fast(c);
            unsigned short hb = f2bf(h);
            int kg = 25*m + f;
            put16(XA1, 48 + kg, r, hb);
            put16(XA2, kg, r, hb);
            PST(&exc[((g*3 + 0)*NM + m)*400 + tid], h);
        }
        if (tid < 768) {
            int r = tid / 48, j = tid % 48;
            float acc = f0bs[j];
            #pragma unroll
            for (int k = 0; k < 24; ++k) {
                float tv = (k < 12) ? st6[r][k % 6] : ac6[r][k % 6];
                acc += tv * fc0s[k * 48 + j];
            }
            put16(XA2, 200 + j, r, f2bf(fmaxf(acc, 0.f)));
        }
        __syncthreads();    // drains vmcnt -> h1 payload in (shared) L2

        // ---- exchange h1 ----
        if (tid == 0) AST(&flg[(g*3 + 0)*NM + m], (unsigned)(t + 1));
        if (tid < 8 && tid != m) {
            while (ALD(&flg[(g*3 + 0)*NM + tid]) != (unsigned)(t + 1))
                __builtin_amdgcn_s_sleep(1);
        }
        __syncthreads();
        for (int q = tid; q < 3200; q += 1024) {
            int mm = q / 400;
            if (mm == m) continue;
            int qq = q % 400, r = qq / 25, f = qq % 25;
            float v = ALD(&exc[((g*3 + 0)*NM + mm)*400 + qq]);
            unsigned short hb = f2bf(v);
            int kg = 25*mm + f;
            put16(XA1, 48 + kg, r, hb);
            put16(XA2, kg, r, hb);
        }
        __syncthreads();

        // ---- B: gates2 = XA2 @ W2_slice (register-resident weights) ----
        if (wave < 7) {
            floatx4 acc = {0.f, 0.f, 0.f, 0.f};
            #pragma unroll
            for (int kf = 0; kf < 14; ++kf)
                acc = __builtin_amdgcn_mfma_f32_16x16x32_bf16(XA2[(kf << 6) + lane], w2r[kf], acc, 0, 0, 0);
            int col = wave * 16 + ln, m0 = hi * 4;
            gates[(m0+0)*GWL + col] = acc[0];
            gates[(m0+1)*GWL + col] = acc[1];
            gates[(m0+2)*GWL + col] = acc[2];
            gates[(m0+3)*GWL + col] = acc[3];
        }
        __syncthreads();

        // ---- pw2: h2/c2; publish h2 ----
        if (tid < 400) {
            int r = tid / 25, f = tid % 25;
            float gi = gates[r*GWL + f]      + b2s[f];
            float gf = gates[r*GWL + 25 + f] + b2s[25 + f];
            float gg = gates[r*GWL + 50 + f] + b2s[50 + f];
            float go = gates[r*GWL + 75 + f] + b2s[75 + f];
            float c = sigm(gf) * c2r + sigm(gi) * tanh_fast(gg);
            c2r = c;
            float h = sigm(go) * tanh_fast(c);
            unsigned short hb = f2bf(h);
            int kg = 25*m + f;
            put16(XA2, 248 + kg, r, hb);
            put16(XA3, kg, r, hb);
            PST(&exc[((g*3 + 1)*NM + m)*400 + tid], h);
        }
        __syncthreads();    // drains vmcnt -> h2 payload in L2

        // ---- exchange h2 ----
        if (tid == 0) AST(&flg[(g*3 + 1)*NM + m], (unsigned)(t + 1));
        if (tid < 8 && tid != m) {
            while (ALD(&flg[(g*3 + 1)*NM + tid]) != (unsigned)(t + 1))
                __builtin_amdgcn_s_sleep(1);
        }
        __syncthreads();
        for (int q = tid; q < 3200; q += 1024) {
            int mm = q / 400;
            if (mm == m) continue;
            int qq = q % 400, r = qq / 25, f = qq % 25;
            float v = ALD(&exc[((g*3 + 1)*NM + mm)*400 + qq]);
            unsigned short hb = f2bf(v);
            int kg = 25*mm + f;
            put16(XA2, 248 + kg, r, hb);
            put16(XA3, kg, r, hb);
        }
        __syncthreads();

        // ---- C: fc1 slice = XA3 @ F1_slice (waves 0..1) ----
        if (wave < 2) {
            floatx4 acc = {0.f, 0.f, 0.f, 0.f};
            const int rbase = (wave * 16 + ln) * 33 + hi;
            #pragma unroll
            for (int kf = 0; kf < 8; ++kf)
                acc = __builtin_amdgcn_mfma_f32_16x16x32_bf16(XA3[(kf << 6) + lane], sF1[rbase + kf*4], acc, 0, 0, 0);
            int col = wave * 16 + ln, m0 = hi * 4;
            gates[(m0+0)*GWL + col] = acc[0];
            gates[(m0+1)*GWL + col] = acc[1];
            gates[(m0+2)*GWL + col] = acc[2];
            gates[(m0+3)*GWL + col] = acc[3];
        }
        __syncthreads();

        // ---- pw3: o3 = tanh; publish o3 ----
        if (tid < 400) {
            int r = tid / 25, f = tid % 25;
            float v = tanh_fast(gates[r*GWL + f] + f1bs[f]);
            put16(XA4, 25*m + f, r, f2bf(v));
            PST(&exc[((g*3 + 2)*NM + m)*400 + tid], v);
        }
        __syncthreads();    // drains vmcnt -> o3 payload in L2

        // ---- exchange o3 ----
        if (tid == 0) AST(&flg[(g*3 + 2)*NM + m], (unsigned)(t + 1));
        if (tid < 8 && tid != m) {
            while (ALD(&flg[(g*3 + 2)*NM + tid]) != (unsigned)(t + 1))
                __builtin_amdgcn_s_sleep(1);
        }
        __syncthreads();
        for (int q = tid; q < 3200; q += 1024) {
            int mm = q / 400;
            if (mm == m) continue;
            int qq = q % 400, r = qq / 25, f = qq % 25;
            float v = ALD(&exc[((g*3 + 2)*NM + mm)*400 + qq]);
            put16(XA4, 25*mm + f, r, f2bf(v));
        }
        __syncthreads();

        // ---- D: fc2 full (redundant in every member; waves 0..2) ----
        if (wave < 3) {
            floatx4 acc = {0.f, 0.f, 0.f, 0.f};
            const int rbase = (wave * 16 + ln) * 29 + hi;
            #pragma unroll
            for (int kf = 0; kf < 7; ++kf)
                acc = __builtin_amdgcn_mfma_f32_16x16x32_bf16(XA4[(kf << 6) + lane], sF2[rbase + kf*4], acc, 0, 0, 0);
            int col = wave * 16 + ln, m0 = hi * 4;
            gates[(m0+0)*GWL + col] = acc[0];
            gates[(m0+1)*GWL + col] = acc[1];
            gates[(m0+2)*GWL + col] = acc[2];
            gates[(m0+3)*GWL + col] = acc[3];
        }
        __syncthreads();

        // ---- pw4: out4 = tanh; store (member 0); feed back as next x ----
        if (tid < 768) {
            int r = tid / 48, j = tid % 48;
            float v = tanh_fast(gates[r*GWL + j] + f2bs[j]);
            unsigned short xb = f2bf(v);
            put16(XA1, j, r, xb);
            put16(XA3, 200 + j, r, xb);
            if (m == 0 && t >= ctx - 1)
                out[((size_t)(t - (ctx - 1)) * BB + r0 + r) * 48 + j] = v;
        }
        __syncthreads();
    }
}

extern "C" void kernel_launch(void* const* d_in, const int* in_sizes, int n_in,
                              void* d_out, int out_size, void* d_ws, size_t ws_size,
                              hipStream_t stream)
{
    const float* tactiles = (const float*)d_in[0];
    const float* actions  = (const float*)d_in[1];
    const float* fc0_w    = (const float*)d_in[2];
    const float* fc0_b    = (const float*)d_in[3];
    const float* l1_wih   = (const float*)d_in[4];
    const float* l1_whh   = (const float*)d_in[5];
    const float* l1_bih   = (const float*)d_in[6];
    const float* l1_bhh   = (const float*)d_in[7];
    const float* l2_wih   = (const float*)d_in[8];
    const float* l2_whh   = (const float*)d_in[9];
    const float* l2_bih   = (const float*)d_in[10];
    const float* l2_bhh   = (const float*)d_in[11];
    const float* fc1_w    = (const float*)d_in[12];
    const float* fc1_b    = (const float*)d_in[13];
    const float* fc2_w    = (const float*)d_in[14];
    const float* fc2_b    = (const float*)d_in[15];
    const int*   ctxp     = (const int*)d_in[16];
    unsigned* ws = (unsigned*)d_ws;
    float* out = (float*)d_out;

    hipLaunchKernelGGL(prep_kernel, dim3(512), dim3(256), 0, stream,
                       l1_wih, l1_whh, l1_bih, l1_bhh,
                       l2_wih, l2_whh, l2_bih, l2_bhh,
                       fc1_w, fc2_w, fc0_w, ws);
    hipLaunchKernelGGL(prep_fc1b, dim3(1), dim3(256), 0, stream, fc1_b, ws);
    hipLaunchKernelGGL(lstm_sync, dim3(256), dim3(1024), 0, stream,
                       tactiles, actions, fc0_b, fc2_b, ctxp, ws, out);
}